// Round 10
// baseline (183.629 us; speedup 1.0000x reference)
//
#include <hip/hip_runtime.h>
#include <hip/hip_bf16.h>
#include <math.h>

// ---------------------------------------------------------------------------
// TernaryLeNet5 forward.
// R9: conv12 de-latencified. R8 showed VALUBusy 50->27 with wall flat at
// 51us: latency/barrier-bound, not pipe-bound. Changes:
//   - conv1 im2col buffer DELETED: each lane builds its A-frag directly
//     from the 2KB sxb image via 8 per-lane ds_read_u16 (tap offsets dj[j]
//     precomputed; taps >=25 masked to 0 -> deterministic, per R8 lesson).
//     Kills 2 barriers, 13.3KB LDS, and all A-write traffic.
//   - sxt stride 40 -> 36 (uniform 2-way banks = free).
//   - LDS 53,248 -> 39,464 B -> 4 blocks/CU: full 1024-block grid
//     co-resident, no tail generation.
// Known: harness's 41us ws-poison fill is inside dur_us (uncontrollable).
// ---------------------------------------------------------------------------

typedef __attribute__((ext_vector_type(8))) short bf16x8;
typedef __attribute__((ext_vector_type(4))) float f32x4;

#define SXT_STRIDE 36   // ushorts per pixel row in sxt ([196][36])

// ---- ws layout (float offsets) --------------------------------------------
// pb: pabs[5][16] @0, ps1[5][16] @80, pcnt[5][16] @160
static const size_t OFF_PB    = 0;        // 240 f32
static const size_t OFF_W1B   = 256;      // [32][32] bf16 = 512 f32
static const size_t OFF_W2B   = 1056;     // [64][25][32] bf16 = 25600 f32
static const size_t OFF_W3B   = 26656;    // [128][1600] bf16  = 102400 f32
static const size_t OFF_FW1T  = 129056;   // [120][84] f32, +-1/0
static const size_t OFF_FW2T  = 139136;   // [84][10] f32, +-1/0
static const size_t OFF_P2B   = 139976;   // [1024][1600] bf16 = 819200 f32
static const size_t OFF_H3    = 959176;   // [1024][120] f32
// total ~4.3 MB

#define BPT 16   // blocks per tensor in ternarize passes

__device__ __forceinline__ ushort f2bf(float v) {   // RNE float->bf16 bits
    unsigned u = __float_as_uint(v);
    unsigned r = (u + 0x7FFFu + ((u >> 16) & 1u)) >> 16;
    return (ushort)r;
}
__device__ __forceinline__ float bf2f(ushort h) {
    return __uint_as_float((unsigned)h << 16);
}

// tanh via hw exp: 1 - 2e/(1+e), e = exp(-2|x|) in (0,1] -> no overflow.
__device__ __forceinline__ float tanh_fast(float x) {
    float e = __expf(-2.0f * fabsf(x));
    float r = 1.0f - 2.0f * e / (1.0f + e);
    return copysignf(r, x);
}

__device__ __forceinline__ void tensor_select(int tensor,
        const float* w1, const float* w2, const float* w3,
        const float* fw1, const float* fw2,
        const float*& src, int& O, int& K) {
    switch (tensor) {
        case 0: src = w1;  O = 32;  K = 25;   break;
        case 1: src = w2;  O = 64;  K = 800;  break;
        case 2: src = w3;  O = 120; K = 1600; break;
        case 3: src = fw1; O = 84;  K = 120;  break;
        default: src = fw2; O = 10; K = 84;   break;
    }
}

__device__ __forceinline__ float block_sum_256(float v, float* sbuf) {
    #pragma unroll
    for (int off = 32; off > 0; off >>= 1) v += __shfl_down(v, off);
    const int wid = threadIdx.x >> 6;
    if ((threadIdx.x & 63) == 0) sbuf[wid] = v;
    __syncthreads();
    return sbuf[0] + sbuf[1] + sbuf[2] + sbuf[3];
}

// alpha for `tensor` from pass2 partials (redundant per-thread compute)
__device__ __forceinline__ float alpha_of(const float* pb, int tensor) {
    float s1 = 0.f, c = 0.f;
    #pragma unroll
    for (int i = 0; i < BPT; ++i) {
        s1 += pb[80 + tensor * BPT + i];
        c  += pb[160 + tensor * BPT + i];
    }
    return s1 / fmaxf(c, 1.0f);
}

// ---------------------------------------------------------------------------
__global__ __launch_bounds__(256)
void tern_pass1(const float* w1, const float* w2, const float* w3,
                const float* fw1, const float* fw2, float* pb) {
    __shared__ float sbuf[4];
    const int tensor = blockIdx.x / BPT;
    const int blk    = blockIdx.x % BPT;
    const float* src; int O, K;
    tensor_select(tensor, w1, w2, w3, fw1, fw2, src, O, K);
    const int n = O * K;
    float s = 0.f;
    for (int i = blk * 256 + threadIdx.x; i < n; i += BPT * 256)
        s += fabsf(src[i]);
    s = block_sum_256(s, sbuf);
    if (threadIdx.x == 0) pb[tensor * BPT + blk] = s;
}

// pass2: delta from pass1 partials; quantize to +-1/0; write masked partials.
__global__ __launch_bounds__(256)
void tern_pass2(const float* w1, const float* w2, const float* w3,
                const float* fw1, const float* fw2,
                ushort* w1b, ushort* w2b, ushort* w3b,
                float* fw1t, float* fw2t, float* pb) {
    __shared__ float sbuf[4];
    const int tensor = blockIdx.x / BPT;
    const int blk    = blockIdx.x % BPT;
    const float* src; int O, K;
    tensor_select(tensor, w1, w2, w3, fw1, fw2, src, O, K);
    const int n = O * K;
    float tot = 0.f;
    #pragma unroll
    for (int i = 0; i < BPT; ++i) tot += pb[tensor * BPT + i];
    const float delta = 0.7f * tot / (float)n;

    const ushort BP = 0x3F80u, BN = 0xBF80u;   // bf16 +1, -1
    float s1 = 0.f, cnt = 0.f;

    if (tensor == 0) {
        // w1 -> bf16 [oc][32]: k 0..24 = taps, k 25..31 = 0 (pads MFMA K)
        for (int j = blk * 256 + threadIdx.x; j < 1024; j += BPT * 256) {
            const int oc = j >> 5, kk = j & 31;
            ushort qb = 0;
            if (kk < 25) {
                float w = src[oc * 25 + kk];
                float aw = fabsf(w);
                if (aw > delta) { s1 += aw; cnt += 1.f; qb = (w > 0.f) ? BP : BN; }
            }
            w1b[j] = qb;
        }
    } else if (tensor == 2) {
        // w3 -> bf16 [oc][1600] row-linear; zero-fill pad rows 120..127
        for (int i = blk * 256 + threadIdx.x; i < 128 * 1600; i += BPT * 256) {
            ushort qb = 0;
            if (i < n) {
                float w = src[i];
                float aw = fabsf(w);
                if (aw > delta) { s1 += aw; cnt += 1.f; qb = (w > 0.f) ? BP : BN; }
            }
            w3b[i] = qb;
        }
    } else if (tensor == 1) {
        // w2 -> bf16 [oc][tap][ic]; src is [oc][ic][kh][kw]
        for (int i = blk * 256 + threadIdx.x; i < n; i += BPT * 256) {
            float w = src[i];
            float aw = fabsf(w);
            ushort qb = 0;
            if (aw > delta) { s1 += aw; cnt += 1.f; qb = (w > 0.f) ? BP : BN; }
            int oc = i / 800;
            int r  = i - oc * 800;
            int ic = r / 25;
            int tap = r - ic * 25;
            w2b[oc * 800 + tap * 32 + ic] = qb;
        }
    } else {
        float* dst = (tensor == 3) ? fw1t : fw2t;
        for (int i = blk * 256 + threadIdx.x; i < n; i += BPT * 256) {
            float w = src[i];
            float aw = fabsf(w);
            float q = 0.f;
            if (aw > delta) { s1 += aw; cnt += 1.f; q = (w > 0.f) ? 1.f : -1.f; }
            int o = i / K;
            int k = i - o * K;
            dst[k * O + o] = q;      // transpose to [k][O]
        }
    }
    s1 = block_sum_256(s1, sbuf);
    __syncthreads();
    cnt = block_sum_256(cnt, sbuf);
    if (threadIdx.x == 0) {
        pb[80 + tensor * BPT + blk]  = s1;
        pb[160 + tensor * BPT + blk] = cnt;
    }
}

// ---------------------------------------------------------------------------
// conv2 MFMA inner (stride 36 sxt)
template<int TBASE, int TCNT>
__device__ __forceinline__ void conv2_phase(
        const ushort* __restrict__ w2b, const ushort* sxt,
        int n0, int mt0, int lane, f32x4 acc[4][2]) {
    const int col = lane & 15, quad = lane >> 4;
    bf16x8 bfr[TCNT][2];
    #pragma unroll
    for (int i = 0; i < TCNT; ++i) {
        const int tap = TBASE + i;
        #pragma unroll
        for (int np = 0; np < 2; ++np) {
            const int oc = n0 + np * 16 + col;
            bfr[i][np] = *(const bf16x8*)(w2b + (oc * 25 + tap) * 32 + quad * 8);
        }
    }
    #pragma unroll
    for (int mi = 0; mi < 4; ++mi) {
        int m = (mt0 + mi) * 16 + col;
        m = m < 100 ? m : 99;                     // clamp padding rows
        const int oh = m / 10, ow = m - oh * 10;
        const ushort* abase = sxt + (oh * 14 + ow) * SXT_STRIDE + quad * 8;
        #pragma unroll
        for (int i = 0; i < TCNT; ++i) {
            const int tap = TBASE + i;
            const int kh = tap / 5, kw = tap - kh * 5;
            bf16x8 af = *(const bf16x8*)(abase + (kh * 14 + kw) * SXT_STRIDE);
            acc[mi][0] = __builtin_amdgcn_mfma_f32_16x16x32_bf16(af, bfr[i][0], acc[mi][0], 0, 0, 0);
            acc[mi][1] = __builtin_amdgcn_mfma_f32_16x16x32_bf16(af, bfr[i][1], acc[mi][1], 0, 0, 0);
        }
    }
}

// ---------------------------------------------------------------------------
// conv12: conv1 (MFMA, A-frags read directly from sxb) + pool + conv2 (MFMA)
// + pool, one image per block.
__global__ __launch_bounds__(256)
void conv12_kernel(const float* __restrict__ x, const ushort* __restrict__ w1b,
                   const float* __restrict__ b1, const ushort* __restrict__ w2b,
                   const float* __restrict__ b2, const float* __restrict__ pb,
                   ushort* __restrict__ p2b) {
    // LDS plan (39,464 B -> 4 blocks/CU):
    //   [0,14112)      sxt  : pooled1 tile [196][36] ushort (phase 2+)
    //                  sxb  : x as bf16 [32][32] overlays [0,2048) (phase 1)
    //   [14112,39328)  hb1  : h-pooled conv1 [32][394] bf16
    //                  hb2  : h-pooled conv2 [64][50] f32 (overlay, phase 3)
    //   [39328,39456)  sbias: b1 [32] f32
    //   [39456,39464)  salpha
    __shared__ __align__(16) char smem[39464];
    ushort* sxb    = (ushort*)smem;
    ushort* sxt    = (ushort*)smem;
    ushort* hb1    = (ushort*)(smem + 14112);
    float*  hb2    = (float*) (smem + 14112);
    float*  sbias  = (float*) (smem + 39328);
    float*  salpha = (float*) (smem + 39456);

    const int n = blockIdx.x;
    const int t = threadIdx.x;
    const int wave = t >> 6, lane = t & 63;
    const int col = lane & 15, quad = lane >> 4;

    // conv1 B-frags from global, issued before the first barrier.
    bf16x8 B0 = *(const bf16x8*)(w1b + col * 32 + quad * 8);
    bf16x8 B1 = *(const bf16x8*)(w1b + (col + 16) * 32 + quad * 8);

    // Per-lane A-frag tap offsets (k = quad*8+j -> tap k if k<25 else zero).
    // Computed once; taps >=25 read offset 0 and are masked to 0 (finite,
    // deterministic -- R8 lesson: never leave MFMA inputs uninitialized).
    int  dj[8];
    bool vj[8];
    {
        const int t0 = quad * 8;
        #pragma unroll
        for (int j = 0; j < 8; ++j) {
            const int tap = t0 + j;
            const int kh = tap / 5, kw = tap - kh * 5;
            vj[j] = (tap < 25);
            dj[j] = vj[j] ? (kh * 32 + kw) : 0;
        }
    }

    {   // stage x -> bf16 sxb
        float4 v = ((const float4*)(x + (size_t)n * 1024))[t];
        ushort4 q;
        q.x = f2bf(v.x); q.y = f2bf(v.y); q.z = f2bf(v.z); q.w = f2bf(v.w);
        *(ushort4*)(sxb + t * 4) = q;
        if (t < 32) sbias[t] = b1[t];
        if (t == 32) salpha[0] = alpha_of(pb, 0);
        if (t == 33) salpha[1] = alpha_of(pb, 1);
    }
    __syncthreads();

    // ---- conv1: 49 tiles of 16 pixels, no intermediate barriers ---------
    for (int tile = wave; tile < 49; tile += 4) {
        const int m = tile * 16 + col;           // A row = pixel
        const int oh = m / 28, ow = m - oh * 28;
        const int base = oh * 32 + ow;
        bf16x8 af;
        #pragma unroll
        for (int j = 0; j < 8; ++j) {
            ushort r = sxb[base + dj[j]];
            af[j] = (short)(vj[j] ? r : (ushort)0);
        }
        f32x4 z = {};
        f32x4 c0 = __builtin_amdgcn_mfma_f32_16x16x32_bf16(af, B0, z, 0, 0, 0);
        f32x4 c1 = __builtin_amdgcn_mfma_f32_16x16x32_bf16(af, B1, z, 0, 0, 0);
        // h-pool: lane owns pixels p..p+3 (consecutive; 4|28 so same row)
        const int p = tile * 16 + quad * 4;
        const int poh = p / 28, pow2 = (p % 28) >> 1;
        ushort2 h0, h1;
        h0.x = f2bf(fmaxf(c0[0], c0[1])); h0.y = f2bf(fmaxf(c0[2], c0[3]));
        h1.x = f2bf(fmaxf(c1[0], c1[1])); h1.y = f2bf(fmaxf(c1[2], c1[3]));
        *(ushort2*)(hb1 + col * 394 + poh * 14 + pow2) = h0;
        *(ushort2*)(hb1 + (col + 16) * 394 + poh * 14 + pow2) = h1;
    }
    __syncthreads();   // hb1 complete; sxb dead after this phase

    // ---- vertical pool + alpha/bias + tanh -> sxt (overlays sxb) --------
    {
        const float a1 = salpha[0];
        for (int idx = t; idx < 6272; idx += 256) {
            const int oc = idx & 31, pos = idx >> 5;     // pos = ph*14+pw
            const int ph = pos / 14, pw = pos - ph * 14;
            const ushort* hp = hb1 + oc * 394 + (2 * ph) * 14 + pw;
            float m = fmaxf(bf2f(hp[0]), bf2f(hp[14]));
            sxt[pos * SXT_STRIDE + oc] = f2bf(tanh_fast(fmaf(a1, m, sbias[oc])));
        }
    }
    __syncthreads();   // sxt ready; hb1 dead

    // ---- conv2 MFMA -----------------------------------------------------
    const int n0  = (wave & 1) * 32;
    const int mt0 = (wave >> 1) * 4;
    f32x4 acc2[4][2] = {};
    conv2_phase<0, 13>(w2b, sxt, n0, mt0, lane, acc2);
    conv2_phase<13, 12>(w2b, sxt, n0, mt0, lane, acc2);

    {   // horizontal pool in-register -> hb2[oc][50] (overlays hb1)
        #pragma unroll
        for (int mi = 0; mi < 4; ++mi) {
            const int mrow = (mt0 + mi) * 16 + quad * 4;
            if (mrow < 100) {
                #pragma unroll
                for (int np = 0; np < 2; ++np) {
                    const int oc = n0 + np * 16 + col;
                    float2 hm;
                    hm.x = fmaxf(acc2[mi][np][0], acc2[mi][np][1]);
                    hm.y = fmaxf(acc2[mi][np][2], acc2[mi][np][3]);
                    *(float2*)(&hb2[oc * 50 + (mrow >> 1)]) = hm;
                }
            }
        }
    }
    __syncthreads();

    // vertical pool + alpha/bias + tanh -> p2b bf16 [n][1600] (k = oc*25+pix)
    const float a2 = salpha[1];
    for (int idx = t; idx < 1600; idx += 256) {
        const int oc = idx / 25, r = idx - oc * 25;
        const int ph = r / 5, pw = r - ph * 5;
        const float* hb = &hb2[oc * 50 + ph * 10 + pw];
        float m = fmaxf(hb[0], hb[5]);
        p2b[(size_t)n * 1600 + idx] = f2bf(tanh_fast(fmaf(a2, m, b2[oc])));
    }
}

// ---------------------------------------------------------------------------
// conv3 as MFMA GEMM: h3[1024][120] = tanh(a3*(P2 x W3^T) + b3)
template<int STEPS>
__device__ __forceinline__ void conv3_chunk(const ushort* Abase, const ushort* B0,
                                            const ushort* B1, f32x4& acc0, f32x4& acc1) {
    #pragma unroll
    for (int s = 0; s < STEPS; ++s) {
        bf16x8 af = *(const bf16x8*)(Abase + s * 32);
        bf16x8 b0 = *(const bf16x8*)(B0 + s * 32);
        bf16x8 b1 = *(const bf16x8*)(B1 + s * 32);
        acc0 = __builtin_amdgcn_mfma_f32_16x16x32_bf16(af, b0, acc0, 0, 0, 0);
        acc1 = __builtin_amdgcn_mfma_f32_16x16x32_bf16(af, b1, acc1, 0, 0, 0);
    }
}

__global__ __launch_bounds__(256)
void conv3_mfma(const ushort* __restrict__ p2b, const ushort* __restrict__ w3b,
                const float* __restrict__ b3, const float* __restrict__ pb,
                float* __restrict__ h3) {
    __shared__ float red[4][64][8];   // [wave][lane][np*4+reg]
    __shared__ float salpha;
    const int t = threadIdx.x;
    const int wave = t >> 6, lane = t & 63;
    const int mt = blockIdx.x >> 2;       // 0..63
    const int npair = blockIdx.x & 3;     // 0..3
    const int col = lane & 15, quad = lane >> 4;
    const int kstart = (wave < 2) ? wave * 13 : 26 + (wave - 2) * 12;  // 0,13,26,38

    if (t == 0) salpha = alpha_of(pb, 2);

    const ushort* Abase = p2b + (size_t)(mt * 16 + col) * 1600 + kstart * 32 + quad * 8;
    const ushort* B0 = w3b + (size_t)(npair * 32 + col) * 1600 + kstart * 32 + quad * 8;
    const ushort* B1 = B0 + 16 * 1600;

    f32x4 acc0 = {}, acc1 = {};
    if (wave < 2) conv3_chunk<13>(Abase, B0, B1, acc0, acc1);
    else          conv3_chunk<12>(Abase, B0, B1, acc0, acc1);

    #pragma unroll
    for (int r = 0; r < 4; ++r) {
        red[wave][lane][r]     = acc0[r];
        red[wave][lane][4 + r] = acc1[r];
    }
    __syncthreads();

    {   // thread t: lane l = t&63, reg vh = t>>6; handles np = 0 and 1
        const float a3 = salpha;
        const int l = t & 63, vh = t >> 6;
        const int lcol = l & 15, lquad = l >> 4;
        const int img = mt * 16 + lquad * 4 + vh;
        #pragma unroll
        for (int j = 0; j < 2; ++j) {
            const int v = j * 4 + vh;
            float s = red[0][l][v] + red[1][l][v] + red[2][l][v] + red[3][l][v];
            const int oc = npair * 32 + j * 16 + lcol;
            if (oc < 120) h3[(size_t)img * 120 + oc] = tanh_fast(fmaf(a3, s, b3[oc]));
        }
    }
}

// ---------------------------------------------------------------------------
// fc1 + tanh + fc2 + softmax. Block per image; alpha folded.
__global__ __launch_bounds__(128)
void fc_kernel(const float* __restrict__ h3, const float* __restrict__ fw1t,
               const float* __restrict__ fb1, const float* __restrict__ fw2t,
               const float* __restrict__ fb2, const float* __restrict__ pb,
               float* __restrict__ out) {
    const int n = blockIdx.x;
    __shared__ float sh[120];
    __shared__ float sh4[84];
    __shared__ float sl[10];
    __shared__ float salpha[2];
    const int t = threadIdx.x;
    if (t < 120) sh[t] = h3[(size_t)n * 120 + t];
    if (t == 120) salpha[0] = alpha_of(pb, 3);
    if (t == 121) salpha[1] = alpha_of(pb, 4);
    __syncthreads();
    if (t < 84) {
        const float af1 = salpha[0];
        float a = 0.f;
        #pragma unroll 4
        for (int k = 0; k < 120; ++k) a = fmaf(fw1t[k * 84 + t], sh[k], a);
        sh4[t] = tanh_fast(fmaf(af1, a, fb1[t]));
    }
    __syncthreads();
    if (t < 10) {
        const float af2 = salpha[1];
        float a = 0.f;
        #pragma unroll 4
        for (int k = 0; k < 84; ++k) a = fmaf(fw2t[k * 10 + t], sh4[k], a);
        const float lg = fmaf(af2, a, fb2[t]);
        sl[t] = lg;
        out[(size_t)n * 10 + t] = lg;
    }
    __syncthreads();
    if (t < 10) {
        float m = -INFINITY;
        #pragma unroll
        for (int i = 0; i < 10; ++i) m = fmaxf(m, sl[i]);
        float s = 0.f;
        #pragma unroll
        for (int i = 0; i < 10; ++i) s += expf(sl[i] - m);
        out[10240 + (size_t)n * 10 + t] = expf(sl[t] - m) / s;
    }
}

// ---------------------------------------------------------------------------
extern "C" void kernel_launch(void* const* d_in, const int* in_sizes, int n_in,
                              void* d_out, int out_size, void* d_ws, size_t ws_size,
                              hipStream_t stream) {
    const float* x   = (const float*)d_in[0];
    const float* w1  = (const float*)d_in[1];
    const float* b1  = (const float*)d_in[2];
    const float* w2  = (const float*)d_in[3];
    const float* b2  = (const float*)d_in[4];
    const float* w3  = (const float*)d_in[5];
    const float* b3  = (const float*)d_in[6];
    const float* fw1 = (const float*)d_in[7];
    const float* fb1 = (const float*)d_in[8];
    const float* fw2 = (const float*)d_in[9];
    const float* fb2 = (const float*)d_in[10];

    float* ws = (float*)d_ws;
    float*  pb   = ws + OFF_PB;
    ushort* w1b  = (ushort*)(ws + OFF_W1B);
    ushort* w2b  = (ushort*)(ws + OFF_W2B);
    ushort* w3b  = (ushort*)(ws + OFF_W3B);
    float*  fw1t = ws + OFF_FW1T;
    float*  fw2t = ws + OFF_FW2T;
    ushort* p2b  = (ushort*)(ws + OFF_P2B);
    float*  h3   = ws + OFF_H3;
    float*  out  = (float*)d_out;

    tern_pass1<<<5 * BPT, 256, 0, stream>>>(w1, w2, w3, fw1, fw2, pb);
    tern_pass2<<<5 * BPT, 256, 0, stream>>>(w1, w2, w3, fw1, fw2,
                                            w1b, w2b, w3b, fw1t, fw2t, pb);
    conv12_kernel<<<1024, 256, 0, stream>>>(x, w1b, b1, w2b, b2, pb, p2b);
    conv3_mfma<<<256, 256, 0, stream>>>(p2b, w3b, b3, pb, h3);
    fc_kernel<<<1024, 128, 0, stream>>>(h3, fw1t, fb1, fw2t, fb2, pb, out);
}

// Round 11
// 179.770 us; speedup vs baseline: 1.0215x; 1.0215x over previous
//
#include <hip/hip_runtime.h>
#include <hip/hip_bf16.h>
#include <math.h>

// ---------------------------------------------------------------------------
// TernaryLeNet5 forward.
// R10: (a) conv12 reverted to R8-exact (im2col MFMA, 53KB LDS, 51.3us —
// empirically best of 3 structures; R9's per-lane gather regressed to 64us
// with ALL pipes more idle: worse latency/ILP, and with the grid co-resident
// wall == per-block critical path). (b) fc fused into conv3 at 256 blocks
// (4 img/block; R4's 64-block fusion failed at 2.7% occupancy — this keeps
// 1024 waves). M rows 4..15 are clamped pads (MFMA waste free: conv3 matrix
// work is 0.16us total). C rows 0..3 (quad 0) = the 4 images -> sh3 ->
// fc1/fc2/softmax in-block. Kills fc kernel + one gap.
// Known: harness's 41us ws-poison fill is inside dur_us (uncontrollable).
// ---------------------------------------------------------------------------

typedef __attribute__((ext_vector_type(8))) short bf16x8;
typedef __attribute__((ext_vector_type(4))) float f32x4;

// ---- ws layout (float offsets) --------------------------------------------
// pb: pabs[5][16] @0, ps1[5][16] @80, pcnt[5][16] @160
static const size_t OFF_PB    = 0;        // 240 f32
static const size_t OFF_W1B   = 256;      // [32][32] bf16 = 512 f32
static const size_t OFF_W2B   = 1056;     // [64][25][32] bf16 = 25600 f32
static const size_t OFF_W3B   = 26656;    // [128][1600] bf16  = 102400 f32
static const size_t OFF_FW1T  = 129056;   // [120][84] f32, +-1/0
static const size_t OFF_FW2T  = 139136;   // [84][10] f32, +-1/0
static const size_t OFF_P2B   = 139976;   // [1024][1600] bf16 = 819200 f32
// total ~3.8 MB

#define BPT 16   // blocks per tensor in ternarize passes

__device__ __forceinline__ ushort f2bf(float v) {   // RNE float->bf16 bits
    unsigned u = __float_as_uint(v);
    unsigned r = (u + 0x7FFFu + ((u >> 16) & 1u)) >> 16;
    return (ushort)r;
}
__device__ __forceinline__ float bf2f(ushort h) {
    return __uint_as_float((unsigned)h << 16);
}

// tanh via hw exp: 1 - 2e/(1+e), e = exp(-2|x|) in (0,1] -> no overflow.
__device__ __forceinline__ float tanh_fast(float x) {
    float e = __expf(-2.0f * fabsf(x));
    float r = 1.0f - 2.0f * e / (1.0f + e);
    return copysignf(r, x);
}

__device__ __forceinline__ void tensor_select(int tensor,
        const float* w1, const float* w2, const float* w3,
        const float* fw1, const float* fw2,
        const float*& src, int& O, int& K) {
    switch (tensor) {
        case 0: src = w1;  O = 32;  K = 25;   break;
        case 1: src = w2;  O = 64;  K = 800;  break;
        case 2: src = w3;  O = 120; K = 1600; break;
        case 3: src = fw1; O = 84;  K = 120;  break;
        default: src = fw2; O = 10; K = 84;   break;
    }
}

__device__ __forceinline__ float block_sum_256(float v, float* sbuf) {
    #pragma unroll
    for (int off = 32; off > 0; off >>= 1) v += __shfl_down(v, off);
    const int wid = threadIdx.x >> 6;
    if ((threadIdx.x & 63) == 0) sbuf[wid] = v;
    __syncthreads();
    return sbuf[0] + sbuf[1] + sbuf[2] + sbuf[3];
}

// alpha for `tensor` from pass2 partials (redundant per-thread compute)
__device__ __forceinline__ float alpha_of(const float* pb, int tensor) {
    float s1 = 0.f, c = 0.f;
    #pragma unroll
    for (int i = 0; i < BPT; ++i) {
        s1 += pb[80 + tensor * BPT + i];
        c  += pb[160 + tensor * BPT + i];
    }
    return s1 / fmaxf(c, 1.0f);
}

// ---------------------------------------------------------------------------
__global__ __launch_bounds__(256)
void tern_pass1(const float* w1, const float* w2, const float* w3,
                const float* fw1, const float* fw2, float* pb) {
    __shared__ float sbuf[4];
    const int tensor = blockIdx.x / BPT;
    const int blk    = blockIdx.x % BPT;
    const float* src; int O, K;
    tensor_select(tensor, w1, w2, w3, fw1, fw2, src, O, K);
    const int n = O * K;
    float s = 0.f;
    for (int i = blk * 256 + threadIdx.x; i < n; i += BPT * 256)
        s += fabsf(src[i]);
    s = block_sum_256(s, sbuf);
    if (threadIdx.x == 0) pb[tensor * BPT + blk] = s;
}

// pass2: delta from pass1 partials; quantize to +-1/0; write masked partials.
__global__ __launch_bounds__(256)
void tern_pass2(const float* w1, const float* w2, const float* w3,
                const float* fw1, const float* fw2,
                ushort* w1b, ushort* w2b, ushort* w3b,
                float* fw1t, float* fw2t, float* pb) {
    __shared__ float sbuf[4];
    const int tensor = blockIdx.x / BPT;
    const int blk    = blockIdx.x % BPT;
    const float* src; int O, K;
    tensor_select(tensor, w1, w2, w3, fw1, fw2, src, O, K);
    const int n = O * K;
    float tot = 0.f;
    #pragma unroll
    for (int i = 0; i < BPT; ++i) tot += pb[tensor * BPT + i];
    const float delta = 0.7f * tot / (float)n;

    const ushort BP = 0x3F80u, BN = 0xBF80u;   // bf16 +1, -1
    float s1 = 0.f, cnt = 0.f;

    if (tensor == 0) {
        // w1 -> bf16 [oc][32]: k 0..24 = taps, k 25..31 = 0 (pads MFMA K)
        for (int j = blk * 256 + threadIdx.x; j < 1024; j += BPT * 256) {
            const int oc = j >> 5, kk = j & 31;
            ushort qb = 0;
            if (kk < 25) {
                float w = src[oc * 25 + kk];
                float aw = fabsf(w);
                if (aw > delta) { s1 += aw; cnt += 1.f; qb = (w > 0.f) ? BP : BN; }
            }
            w1b[j] = qb;
        }
    } else if (tensor == 2) {
        // w3 -> bf16 [oc][1600] row-linear; zero-fill pad rows 120..127
        for (int i = blk * 256 + threadIdx.x; i < 128 * 1600; i += BPT * 256) {
            ushort qb = 0;
            if (i < n) {
                float w = src[i];
                float aw = fabsf(w);
                if (aw > delta) { s1 += aw; cnt += 1.f; qb = (w > 0.f) ? BP : BN; }
            }
            w3b[i] = qb;
        }
    } else if (tensor == 1) {
        // w2 -> bf16 [oc][tap][ic]; src is [oc][ic][kh][kw]
        for (int i = blk * 256 + threadIdx.x; i < n; i += BPT * 256) {
            float w = src[i];
            float aw = fabsf(w);
            ushort qb = 0;
            if (aw > delta) { s1 += aw; cnt += 1.f; qb = (w > 0.f) ? BP : BN; }
            int oc = i / 800;
            int r  = i - oc * 800;
            int ic = r / 25;
            int tap = r - ic * 25;
            w2b[oc * 800 + tap * 32 + ic] = qb;
        }
    } else {
        float* dst = (tensor == 3) ? fw1t : fw2t;
        for (int i = blk * 256 + threadIdx.x; i < n; i += BPT * 256) {
            float w = src[i];
            float aw = fabsf(w);
            float q = 0.f;
            if (aw > delta) { s1 += aw; cnt += 1.f; q = (w > 0.f) ? 1.f : -1.f; }
            int o = i / K;
            int k = i - o * K;
            dst[k * O + o] = q;      // transpose to [k][O]
        }
    }
    s1 = block_sum_256(s1, sbuf);
    __syncthreads();
    cnt = block_sum_256(cnt, sbuf);
    if (threadIdx.x == 0) {
        pb[80 + tensor * BPT + blk]  = s1;
        pb[160 + tensor * BPT + blk] = cnt;
    }
}

// ---------------------------------------------------------------------------
// conv2 MFMA inner (R8-exact, stride 40 sxt)
template<int TBASE, int TCNT>
__device__ __forceinline__ void conv2_phase(
        const ushort* __restrict__ w2b, const ushort* sxt,
        int n0, int mt0, int lane, f32x4 acc[4][2]) {
    const int col = lane & 15, quad = lane >> 4;
    bf16x8 bfr[TCNT][2];
    #pragma unroll
    for (int i = 0; i < TCNT; ++i) {
        const int tap = TBASE + i;
        #pragma unroll
        for (int np = 0; np < 2; ++np) {
            const int oc = n0 + np * 16 + col;
            bfr[i][np] = *(const bf16x8*)(w2b + (oc * 25 + tap) * 32 + quad * 8);
        }
    }
    #pragma unroll
    for (int mi = 0; mi < 4; ++mi) {
        int m = (mt0 + mi) * 16 + col;
        m = m < 100 ? m : 99;                     // clamp padding rows
        const int oh = m / 10, ow = m - oh * 10;
        const ushort* abase = sxt + (oh * 14 + ow) * 40 + quad * 8;
        #pragma unroll
        for (int i = 0; i < TCNT; ++i) {
            const int tap = TBASE + i;
            const int kh = tap / 5, kw = tap - kh * 5;
            bf16x8 af = *(const bf16x8*)(abase + (kh * 14 + kw) * 40);
            acc[mi][0] = __builtin_amdgcn_mfma_f32_16x16x32_bf16(af, bfr[i][0], acc[mi][0], 0, 0, 0);
            acc[mi][1] = __builtin_amdgcn_mfma_f32_16x16x32_bf16(af, bfr[i][1], acc[mi][1], 0, 0, 0);
        }
    }
}

// ---------------------------------------------------------------------------
// conv12 (R8-exact): conv1 MFMA via in-LDS im2col + pool + conv2 MFMA + pool.
__global__ __launch_bounds__(256)
void conv12_kernel(const float* __restrict__ x, const ushort* __restrict__ w1b,
                   const float* __restrict__ b1, const ushort* __restrict__ w2b,
                   const float* __restrict__ b2, const float* __restrict__ pb,
                   ushort* __restrict__ p2b) {
    __shared__ __align__(16) char smem[53008];
    ushort* sxb    = (ushort*)smem;
    ushort* A      = (ushort*)(smem + 2048);
    ushort* sxt    = (ushort*)(smem + 2048);
    ushort* hb1    = (ushort*)(smem + 27648);
    float*  hb2    = (float*) (smem + 27648);
    float*  sbias  = (float*) (smem + 52864);
    float*  salpha = (float*) (smem + 52992);

    const int n = blockIdx.x;
    const int t = threadIdx.x;
    const int wave = t >> 6, lane = t & 63;
    const int col = lane & 15, quad = lane >> 4;

    bf16x8 B0 = *(const bf16x8*)(w1b + col * 32 + quad * 8);
    bf16x8 B1 = *(const bf16x8*)(w1b + (col + 16) * 32 + quad * 8);

    {   // stage x -> bf16
        float4 v = ((const float4*)(x + (size_t)n * 1024))[t];
        ushort4 q;
        q.x = f2bf(v.x); q.y = f2bf(v.y); q.z = f2bf(v.z); q.w = f2bf(v.w);
        *(ushort4*)(sxb + t * 4) = q;
        if (t < 32) sbias[t] = b1[t];
        if (t == 32) salpha[0] = alpha_of(pb, 0);
        if (t == 33) salpha[1] = alpha_of(pb, 1);
    }
    __syncthreads();

    // ---- conv1: two pixel-halves ----------------------------------------
    for (int half = 0; half < 2; ++half) {
        const int base   = half ? 400 : 0;
        const int rows   = half ? 384 : 400;
        const int ntiles = half ? 24  : 25;

        for (int p = base + t; p < base + rows; p += 256) {
            const int pl = p - base;
            const int oh = p / 28, ow = p % 28;
            ushort v[25];
            #pragma unroll
            for (int kh = 0; kh < 5; ++kh) {
                const ushort* r = sxb + (oh + kh) * 32 + ow;
                v[kh * 5 + 0] = r[0]; v[kh * 5 + 1] = r[1]; v[kh * 5 + 2] = r[2];
                v[kh * 5 + 3] = r[3]; v[kh * 5 + 4] = r[4];
            }
            unsigned d[16];
            #pragma unroll
            for (int j = 0; j < 12; ++j)
                d[j] = (unsigned)v[2 * j] | ((unsigned)v[2 * j + 1] << 16);
            d[12] = (unsigned)v[24];
            d[13] = 0u; d[14] = 0u; d[15] = 0u;   // cols 26..31 zero (determinism)
            uint4* arow = (uint4*)(A + pl * 32);
            uint4 w0; w0.x = d[0];  w0.y = d[1];  w0.z = d[2];  w0.w = d[3];
            uint4 w1; w1.x = d[4];  w1.y = d[5];  w1.z = d[6];  w1.w = d[7];
            uint4 w2; w2.x = d[8];  w2.y = d[9];  w2.z = d[10]; w2.w = d[11];
            uint4 w3; w3.x = d[12]; w3.y = d[13]; w3.z = d[14]; w3.w = d[15];
            arow[0] = w0; arow[1] = w1; arow[2] = w2; arow[3] = w3;
        }
        __syncthreads();

        for (int tile = wave; tile < ntiles; tile += 4) {
            bf16x8 af = *(const bf16x8*)(A + (tile * 16 + col) * 32 + quad * 8);
            f32x4 z = {};
            f32x4 c0 = __builtin_amdgcn_mfma_f32_16x16x32_bf16(af, B0, z, 0, 0, 0);
            f32x4 c1 = __builtin_amdgcn_mfma_f32_16x16x32_bf16(af, B1, z, 0, 0, 0);
            const int p = base + tile * 16 + quad * 4;
            const int oh = p / 28, ow2 = (p % 28) >> 1;
            ushort2 h0, h1;
            h0.x = f2bf(fmaxf(c0[0], c0[1])); h0.y = f2bf(fmaxf(c0[2], c0[3]));
            h1.x = f2bf(fmaxf(c1[0], c1[1])); h1.y = f2bf(fmaxf(c1[2], c1[3]));
            *(ushort2*)(hb1 + col * 394 + oh * 14 + ow2) = h0;
            *(ushort2*)(hb1 + (col + 16) * 394 + oh * 14 + ow2) = h1;
        }
        __syncthreads();
    }

    // ---- vertical pool + alpha/bias + tanh -> sxt (overlays A) ----------
    {
        const float a1 = salpha[0];
        for (int idx = t; idx < 6272; idx += 256) {
            const int oc = idx & 31, pos = idx >> 5;
            const int ph = pos / 14, pw = pos - ph * 14;
            const ushort* hp = hb1 + oc * 394 + (2 * ph) * 14 + pw;
            float m = fmaxf(bf2f(hp[0]), bf2f(hp[14]));
            sxt[pos * 40 + oc] = f2bf(tanh_fast(fmaf(a1, m, sbias[oc])));
        }
    }
    __syncthreads();

    // ---- conv2 MFMA -----------------------------------------------------
    const int n0  = (wave & 1) * 32;
    const int mt0 = (wave >> 1) * 4;
    f32x4 acc2[4][2] = {};
    conv2_phase<0, 13>(w2b, sxt, n0, mt0, lane, acc2);
    conv2_phase<13, 12>(w2b, sxt, n0, mt0, lane, acc2);

    {   // horizontal pool in-register -> hb2[oc][50] (overlays hb1)
        #pragma unroll
        for (int mi = 0; mi < 4; ++mi) {
            const int mrow = (mt0 + mi) * 16 + quad * 4;
            if (mrow < 100) {
                #pragma unroll
                for (int np = 0; np < 2; ++np) {
                    const int oc = n0 + np * 16 + col;
                    float2 hm;
                    hm.x = fmaxf(acc2[mi][np][0], acc2[mi][np][1]);
                    hm.y = fmaxf(acc2[mi][np][2], acc2[mi][np][3]);
                    *(float2*)(&hb2[oc * 50 + (mrow >> 1)]) = hm;
                }
            }
        }
    }
    __syncthreads();

    const float a2 = salpha[1];
    for (int idx = t; idx < 1600; idx += 256) {
        const int oc = idx / 25, r = idx - oc * 25;
        const int ph = r / 5, pw = r - ph * 5;
        const float* hb = &hb2[oc * 50 + ph * 10 + pw];
        float m = fmaxf(hb[0], hb[5]);
        p2b[(size_t)n * 1600 + idx] = f2bf(tanh_fast(fmaf(a2, m, b2[oc])));
    }
}

// ---------------------------------------------------------------------------
// conv3fc: 256 blocks x 4 images. Wave w -> oc 32w..32w+31, full K=50 steps.
// A rows 4..15 are clamped pads (discarded). C rows 0..3 (quad 0) = images
// -> sh3 -> fc1 -> fc2 -> softmax -> out.
__global__ __launch_bounds__(256)
void conv3fc_kernel(const ushort* __restrict__ p2b, const ushort* __restrict__ w3b,
                    const float* __restrict__ b3, const float* __restrict__ fw1t,
                    const float* __restrict__ fb1, const float* __restrict__ fw2t,
                    const float* __restrict__ fb2, const float* __restrict__ pb,
                    float* __restrict__ out) {
    __shared__ float sh3[4][120];
    __shared__ float sh4[4][84];
    __shared__ float slog[4][10];
    __shared__ float salpha[3];
    const int t = threadIdx.x;
    const int wave = t >> 6, lane = t & 63;
    const int col = lane & 15, quad = lane >> 4;
    const int i0 = blockIdx.x * 4;

    if (t < 3) salpha[t] = alpha_of(pb, t + 2);

    // A-frag: row col -> image i0+col for col<4, clamp to i0+3 otherwise
    // (finite + deterministic; rows 4..15 of C are discarded).
    const int img = i0 + (col < 4 ? col : 3);
    const ushort* Abase = p2b + (size_t)img * 1600 + quad * 8;
    const ushort* B0 = w3b + (size_t)(wave * 32 + col) * 1600 + quad * 8;
    const ushort* B1 = B0 + 16 * 1600;

    f32x4 acc0 = {}, acc1 = {};
    #pragma unroll 5
    for (int s = 0; s < 50; ++s) {
        bf16x8 af = *(const bf16x8*)(Abase + s * 32);
        bf16x8 b0 = *(const bf16x8*)(B0 + s * 32);
        bf16x8 b1 = *(const bf16x8*)(B1 + s * 32);
        acc0 = __builtin_amdgcn_mfma_f32_16x16x32_bf16(af, b0, acc0, 0, 0, 0);
        acc1 = __builtin_amdgcn_mfma_f32_16x16x32_bf16(af, b1, acc1, 0, 0, 0);
    }
    __syncthreads();   // salpha visible

    if (quad == 0) {   // lanes 0..15 hold C rows 0..3 = the 4 images
        const float a3 = salpha[0];
        #pragma unroll
        for (int r = 0; r < 4; ++r) {
            const int oc0 = wave * 32 + col;            // 0..111, always <120
            sh3[r][oc0] = tanh_fast(fmaf(a3, acc0[r], b3[oc0]));
            const int oc1 = oc0 + 16;
            if (oc1 < 120) sh3[r][oc1] = tanh_fast(fmaf(a3, acc1[r], b3[oc1]));
        }
    }
    __syncthreads();

    // fc1: 4*84 = 336 outputs
    {
        const float af1 = salpha[1];
        for (int idx = t; idx < 336; idx += 256) {
            const int im = idx / 84, oc = idx - im * 84;
            float s = 0.f;
            #pragma unroll 4
            for (int k = 0; k < 120; ++k) s = fmaf(fw1t[k * 84 + oc], sh3[im][k], s);
            sh4[im][oc] = tanh_fast(fmaf(af1, s, fb1[oc]));
        }
    }
    __syncthreads();

    // fc2 + logits: 40 outputs
    if (t < 40) {
        const float af2 = salpha[2];
        const int im = t / 10, oc = t - im * 10;
        float s = 0.f;
        #pragma unroll 4
        for (int k = 0; k < 84; ++k) s = fmaf(fw2t[k * 10 + oc], sh4[im][k], s);
        const float lg = fmaf(af2, s, fb2[oc]);
        slog[im][oc] = lg;
        out[(size_t)(i0 + im) * 10 + oc] = lg;
    }
    __syncthreads();

    // softmax
    if (t < 40) {
        const int im = t / 10, oc = t - im * 10;
        float m = -INFINITY;
        #pragma unroll
        for (int i = 0; i < 10; ++i) m = fmaxf(m, slog[im][i]);
        float ssum = 0.f;
        #pragma unroll
        for (int i = 0; i < 10; ++i) ssum += expf(slog[im][i] - m);
        out[10240 + (size_t)(i0 + im) * 10 + oc] = expf(slog[im][oc] - m) / ssum;
    }
}

// ---------------------------------------------------------------------------
extern "C" void kernel_launch(void* const* d_in, const int* in_sizes, int n_in,
                              void* d_out, int out_size, void* d_ws, size_t ws_size,
                              hipStream_t stream) {
    const float* x   = (const float*)d_in[0];
    const float* w1  = (const float*)d_in[1];
    const float* b1  = (const float*)d_in[2];
    const float* w2  = (const float*)d_in[3];
    const float* b2  = (const float*)d_in[4];
    const float* w3  = (const float*)d_in[5];
    const float* b3  = (const float*)d_in[6];
    const float* fw1 = (const float*)d_in[7];
    const float* fb1 = (const float*)d_in[8];
    const float* fw2 = (const float*)d_in[9];
    const float* fb2 = (const float*)d_in[10];

    float* ws = (float*)d_ws;
    float*  pb   = ws + OFF_PB;
    ushort* w1b  = (ushort*)(ws + OFF_W1B);
    ushort* w2b  = (ushort*)(ws + OFF_W2B);
    ushort* w3b  = (ushort*)(ws + OFF_W3B);
    float*  fw1t = ws + OFF_FW1T;
    float*  fw2t = ws + OFF_FW2T;
    ushort* p2b  = (ushort*)(ws + OFF_P2B);
    float*  out  = (float*)d_out;

    tern_pass1<<<5 * BPT, 256, 0, stream>>>(w1, w2, w3, fw1, fw2, pb);
    tern_pass2<<<5 * BPT, 256, 0, stream>>>(w1, w2, w3, fw1, fw2,
                                            w1b, w2b, w3b, fw1t, fw2t, pb);
    conv12_kernel<<<1024, 256, 0, stream>>>(x, w1b, b1, w2b, b2, pb, p2b);
    conv3fc_kernel<<<256, 256, 0, stream>>>(p2b, w3b, b3, fw1t, fb1,
                                            fw2t, fb2, pb, out);
}

// Round 12
// 162.120 us; speedup vs baseline: 1.1327x; 1.1089x over previous
//
#include <hip/hip_runtime.h>
#include <hip/hip_bf16.h>
#include <math.h>

// ---------------------------------------------------------------------------
// TernaryLeNet5 forward.
// R11: (a) conv3fc un-fused back to conv3_mfma(256blk)+fc(1024blk) — the
// fused 256-block version measured ~43us (just under top-5 cutoff), no
// better than split, and hides profile visibility. (b) conv12 re-tiled for
// 4 blocks/CU: conv1 im2col in 4 chunks (13/13/13/10 tiles), A buffer
// 208 rows x stride-36 u16 (72B rows: banks 18r mod 32 = all-distinct ->
// conflict-free writes AND frag reads; stride-32 was 8-way), hb1 as
// [392][32], sxb overlaid on hb1 tail (pos>=360 written only by chunk3
// MFMA after sxb dead). LDS 53008 -> 40776 B -> full grid co-resident.
// Cross-session note: identical code drifted 51.3->44.2us between sessions
// (~15%) — only compare within-run.
// Known: harness's ~41us ws-poison fill is inside dur_us (uncontrollable).
// ---------------------------------------------------------------------------

typedef __attribute__((ext_vector_type(8))) short bf16x8;
typedef __attribute__((ext_vector_type(4))) float f32x4;

// ---- ws layout (float offsets) --------------------------------------------
// pb: pabs[5][16] @0, ps1[5][16] @80, pcnt[5][16] @160
static const size_t OFF_PB    = 0;        // 240 f32
static const size_t OFF_W1B   = 256;      // [32][32] bf16 = 512 f32
static const size_t OFF_W2B   = 1056;     // [64][25][32] bf16 = 25600 f32
static const size_t OFF_W3B   = 26656;    // [128][1600] bf16  = 102400 f32
static const size_t OFF_FW1T  = 129056;   // [120][84] f32, +-1/0
static const size_t OFF_FW2T  = 139136;   // [84][10] f32, +-1/0
static const size_t OFF_P2B   = 139976;   // [1024][1600] bf16 = 819200 f32
static const size_t OFF_H3    = 959176;   // [1024][120] f32
// total ~4.3 MB

#define BPT 16   // blocks per tensor in ternarize passes

__device__ __forceinline__ ushort f2bf(float v) {   // RNE float->bf16 bits
    unsigned u = __float_as_uint(v);
    unsigned r = (u + 0x7FFFu + ((u >> 16) & 1u)) >> 16;
    return (ushort)r;
}
__device__ __forceinline__ float bf2f(ushort h) {
    return __uint_as_float((unsigned)h << 16);
}

// tanh via hw exp: 1 - 2e/(1+e), e = exp(-2|x|) in (0,1] -> no overflow.
__device__ __forceinline__ float tanh_fast(float x) {
    float e = __expf(-2.0f * fabsf(x));
    float r = 1.0f - 2.0f * e / (1.0f + e);
    return copysignf(r, x);
}

__device__ __forceinline__ void tensor_select(int tensor,
        const float* w1, const float* w2, const float* w3,
        const float* fw1, const float* fw2,
        const float*& src, int& O, int& K) {
    switch (tensor) {
        case 0: src = w1;  O = 32;  K = 25;   break;
        case 1: src = w2;  O = 64;  K = 800;  break;
        case 2: src = w3;  O = 120; K = 1600; break;
        case 3: src = fw1; O = 84;  K = 120;  break;
        default: src = fw2; O = 10; K = 84;   break;
    }
}

__device__ __forceinline__ float block_sum_256(float v, float* sbuf) {
    #pragma unroll
    for (int off = 32; off > 0; off >>= 1) v += __shfl_down(v, off);
    const int wid = threadIdx.x >> 6;
    if ((threadIdx.x & 63) == 0) sbuf[wid] = v;
    __syncthreads();
    return sbuf[0] + sbuf[1] + sbuf[2] + sbuf[3];
}

// alpha for `tensor` from pass2 partials (redundant per-thread compute)
__device__ __forceinline__ float alpha_of(const float* pb, int tensor) {
    float s1 = 0.f, c = 0.f;
    #pragma unroll
    for (int i = 0; i < BPT; ++i) {
        s1 += pb[80 + tensor * BPT + i];
        c  += pb[160 + tensor * BPT + i];
    }
    return s1 / fmaxf(c, 1.0f);
}

// ---------------------------------------------------------------------------
__global__ __launch_bounds__(256)
void tern_pass1(const float* w1, const float* w2, const float* w3,
                const float* fw1, const float* fw2, float* pb) {
    __shared__ float sbuf[4];
    const int tensor = blockIdx.x / BPT;
    const int blk    = blockIdx.x % BPT;
    const float* src; int O, K;
    tensor_select(tensor, w1, w2, w3, fw1, fw2, src, O, K);
    const int n = O * K;
    float s = 0.f;
    for (int i = blk * 256 + threadIdx.x; i < n; i += BPT * 256)
        s += fabsf(src[i]);
    s = block_sum_256(s, sbuf);
    if (threadIdx.x == 0) pb[tensor * BPT + blk] = s;
}

// pass2: delta from pass1 partials; quantize to +-1/0; write masked partials.
__global__ __launch_bounds__(256)
void tern_pass2(const float* w1, const float* w2, const float* w3,
                const float* fw1, const float* fw2,
                ushort* w1b, ushort* w2b, ushort* w3b,
                float* fw1t, float* fw2t, float* pb) {
    __shared__ float sbuf[4];
    const int tensor = blockIdx.x / BPT;
    const int blk    = blockIdx.x % BPT;
    const float* src; int O, K;
    tensor_select(tensor, w1, w2, w3, fw1, fw2, src, O, K);
    const int n = O * K;
    float tot = 0.f;
    #pragma unroll
    for (int i = 0; i < BPT; ++i) tot += pb[tensor * BPT + i];
    const float delta = 0.7f * tot / (float)n;

    const ushort BP = 0x3F80u, BN = 0xBF80u;   // bf16 +1, -1
    float s1 = 0.f, cnt = 0.f;

    if (tensor == 0) {
        // w1 -> bf16 [oc][32]: k 0..24 = taps, k 25..31 = 0 (pads MFMA K)
        for (int j = blk * 256 + threadIdx.x; j < 1024; j += BPT * 256) {
            const int oc = j >> 5, kk = j & 31;
            ushort qb = 0;
            if (kk < 25) {
                float w = src[oc * 25 + kk];
                float aw = fabsf(w);
                if (aw > delta) { s1 += aw; cnt += 1.f; qb = (w > 0.f) ? BP : BN; }
            }
            w1b[j] = qb;
        }
    } else if (tensor == 2) {
        // w3 -> bf16 [oc][1600] row-linear; zero-fill pad rows 120..127
        for (int i = blk * 256 + threadIdx.x; i < 128 * 1600; i += BPT * 256) {
            ushort qb = 0;
            if (i < n) {
                float w = src[i];
                float aw = fabsf(w);
                if (aw > delta) { s1 += aw; cnt += 1.f; qb = (w > 0.f) ? BP : BN; }
            }
            w3b[i] = qb;
        }
    } else if (tensor == 1) {
        // w2 -> bf16 [oc][tap][ic]; src is [oc][ic][kh][kw]
        for (int i = blk * 256 + threadIdx.x; i < n; i += BPT * 256) {
            float w = src[i];
            float aw = fabsf(w);
            ushort qb = 0;
            if (aw > delta) { s1 += aw; cnt += 1.f; qb = (w > 0.f) ? BP : BN; }
            int oc = i / 800;
            int r  = i - oc * 800;
            int ic = r / 25;
            int tap = r - ic * 25;
            w2b[oc * 800 + tap * 32 + ic] = qb;
        }
    } else {
        float* dst = (tensor == 3) ? fw1t : fw2t;
        for (int i = blk * 256 + threadIdx.x; i < n; i += BPT * 256) {
            float w = src[i];
            float aw = fabsf(w);
            float q = 0.f;
            if (aw > delta) { s1 += aw; cnt += 1.f; q = (w > 0.f) ? 1.f : -1.f; }
            int o = i / K;
            int k = i - o * K;
            dst[k * O + o] = q;      // transpose to [k][O]
        }
    }
    s1 = block_sum_256(s1, sbuf);
    __syncthreads();
    cnt = block_sum_256(cnt, sbuf);
    if (threadIdx.x == 0) {
        pb[80 + tensor * BPT + blk]  = s1;
        pb[160 + tensor * BPT + blk] = cnt;
    }
}

// ---------------------------------------------------------------------------
// conv2 MFMA inner (stride 40 sxt)
template<int TBASE, int TCNT>
__device__ __forceinline__ void conv2_phase(
        const ushort* __restrict__ w2b, const ushort* sxt,
        int n0, int mt0, int lane, f32x4 acc[4][2]) {
    const int col = lane & 15, quad = lane >> 4;
    bf16x8 bfr[TCNT][2];
    #pragma unroll
    for (int i = 0; i < TCNT; ++i) {
        const int tap = TBASE + i;
        #pragma unroll
        for (int np = 0; np < 2; ++np) {
            const int oc = n0 + np * 16 + col;
            bfr[i][np] = *(const bf16x8*)(w2b + (oc * 25 + tap) * 32 + quad * 8);
        }
    }
    #pragma unroll
    for (int mi = 0; mi < 4; ++mi) {
        int m = (mt0 + mi) * 16 + col;
        m = m < 100 ? m : 99;                     // clamp padding rows
        const int oh = m / 10, ow = m - oh * 10;
        const ushort* abase = sxt + (oh * 14 + ow) * 40 + quad * 8;
        #pragma unroll
        for (int i = 0; i < TCNT; ++i) {
            const int tap = TBASE + i;
            const int kh = tap / 5, kw = tap - kh * 5;
            bf16x8 af = *(const bf16x8*)(abase + (kh * 14 + kw) * 40);
            acc[mi][0] = __builtin_amdgcn_mfma_f32_16x16x32_bf16(af, bfr[i][0], acc[mi][0], 0, 0, 0);
            acc[mi][1] = __builtin_amdgcn_mfma_f32_16x16x32_bf16(af, bfr[i][1], acc[mi][1], 0, 0, 0);
        }
    }
}

// ---------------------------------------------------------------------------
// conv12: conv1 MFMA (4-chunk im2col, conflict-free stride-36 A) + pool +
// conv2 MFMA + pool. One image per block, 4 blocks/CU.
__global__ __launch_bounds__(256)
void conv12_kernel(const float* __restrict__ x, const ushort* __restrict__ w1b,
                   const float* __restrict__ b1, const ushort* __restrict__ w2b,
                   const float* __restrict__ b2, const float* __restrict__ pb,
                   ushort* __restrict__ p2b) {
    // LDS 40776 B -> 4 blocks/CU:
    //   [0,15680)      A (chunk im2col [208][36] u16, 14976B) / sxt [196][40]
    //   [15680,40768)  hb1 [392][32] u16 / hb2 [64][50] f32 overlay
    //   [38720,40768)  sxb [32][32] u16 — overlays hb1 tail (pos>=360),
    //                  first written by chunk3 MFMA (pixels>=720), after the
    //                  barrier that ends sxb's last read. Safe.
    //   [40768,40776)  salpha[2]
    __shared__ __align__(16) char smem[40776];
    ushort* A      = (ushort*)smem;
    ushort* sxt    = (ushort*)smem;
    ushort* hb1    = (ushort*)(smem + 15680);
    float*  hb2    = (float*) (smem + 15680);
    ushort* sxb    = (ushort*)(smem + 38720);
    float*  salpha = (float*) (smem + 40768);

    const int n = blockIdx.x;
    const int t = threadIdx.x;
    const int wave = t >> 6, lane = t & 63;
    const int col = lane & 15, quad = lane >> 4;

    // conv1 B-frags + per-thread bias, loaded pre-barrier.
    bf16x8 B0 = *(const bf16x8*)(w1b + col * 32 + quad * 8);
    bf16x8 B1 = *(const bf16x8*)(w1b + (col + 16) * 32 + quad * 8);
    const float b1reg = b1[t & 31];

    {   // stage x -> bf16 sxb
        float4 v = ((const float4*)(x + (size_t)n * 1024))[t];
        ushort4 q;
        q.x = f2bf(v.x); q.y = f2bf(v.y); q.z = f2bf(v.z); q.w = f2bf(v.w);
        *(ushort4*)(sxb + t * 4) = q;
        if (t == 0) salpha[0] = alpha_of(pb, 0);
        if (t == 1) salpha[1] = alpha_of(pb, 1);
    }
    __syncthreads();

    // ---- conv1: 4 chunks of tiles {13,13,13,10} -------------------------
    #pragma unroll
    for (int c = 0; c < 4; ++c) {
        const int tbase = c * 13;
        const int ct    = (c == 3) ? 10 : 13;
        const int pbase = tbase * 16;
        const int rows  = ct * 16;

        // im2col chunk: A[r][k] = x_bf16 taps; cols 25..31 zero (determinism)
        for (int r = t; r < rows; r += 256) {
            const int p = pbase + r;
            const int oh = p / 28, ow = p % 28;
            ushort v[25];
            #pragma unroll
            for (int kh = 0; kh < 5; ++kh) {
                const ushort* rr = sxb + (oh + kh) * 32 + ow;
                v[kh*5+0]=rr[0]; v[kh*5+1]=rr[1]; v[kh*5+2]=rr[2];
                v[kh*5+3]=rr[3]; v[kh*5+4]=rr[4];
            }
            uint2* arow = (uint2*)(A + r * 36);   // 72B rows: banks 18r%32
            #pragma unroll
            for (int j = 0; j < 6; ++j) {
                uint2 w;
                w.x = (unsigned)v[4*j]   | ((unsigned)v[4*j+1] << 16);
                w.y = (unsigned)v[4*j+2] | ((unsigned)v[4*j+3] << 16);
                arow[j] = w;
            }
            uint2 w6; w6.x = (unsigned)v[24]; w6.y = 0u;
            arow[6] = w6;                          // cols 24..27
            uint2 w7; w7.x = 0u; w7.y = 0u;
            arow[7] = w7;                          // cols 28..31
        }
        __syncthreads();

        // MFMA + in-register h-pool -> hb1 [pos][32]
        for (int tl = wave; tl < ct; tl += 4) {
            const ushort* ap = A + (tl * 16 + col) * 36 + quad * 8;
            ushort4 lo = *(const ushort4*)ap;      // 8B-aligned pair
            ushort4 hi = *(const ushort4*)(ap + 4);
            bf16x8 af;
            af[0]=(short)lo.x; af[1]=(short)lo.y; af[2]=(short)lo.z; af[3]=(short)lo.w;
            af[4]=(short)hi.x; af[5]=(short)hi.y; af[6]=(short)hi.z; af[7]=(short)hi.w;
            f32x4 z = {};
            f32x4 c0 = __builtin_amdgcn_mfma_f32_16x16x32_bf16(af, B0, z, 0, 0, 0);
            f32x4 c1 = __builtin_amdgcn_mfma_f32_16x16x32_bf16(af, B1, z, 0, 0, 0);
            // lane owns pixels p..p+3 (4|28 -> same image row)
            const int p = pbase + tl * 16 + quad * 4;
            const int oh = p / 28, ow2 = (p % 28) >> 1;
            const int pos = oh * 14 + ow2;
            hb1[pos * 32 + col]            = f2bf(fmaxf(c0[0], c0[1]));
            hb1[(pos + 1) * 32 + col]      = f2bf(fmaxf(c0[2], c0[3]));
            hb1[pos * 32 + col + 16]       = f2bf(fmaxf(c1[0], c1[1]));
            hb1[(pos + 1) * 32 + col + 16] = f2bf(fmaxf(c1[2], c1[3]));
        }
        __syncthreads();
    }

    // ---- vertical pool + alpha/bias + tanh -> sxt (overlays A) ----------
    {
        const float a1 = salpha[0];
        const int oc = t & 31;                     // == idx&31 every iter
        for (int idx = t; idx < 6272; idx += 256) {
            const int pos2 = idx >> 5;             // 0..195 = ph*14+pw
            const int ph = pos2 / 14, pw = pos2 - ph * 14;
            const int in0 = (2 * ph) * 14 + pw;
            float m = fmaxf(bf2f(hb1[in0 * 32 + oc]),
                            bf2f(hb1[(in0 + 14) * 32 + oc]));
            sxt[pos2 * 40 + oc] = f2bf(tanh_fast(fmaf(a1, m, b1reg)));
        }
    }
    __syncthreads();   // sxt ready; hb1 dead

    // ---- conv2 MFMA -----------------------------------------------------
    const int n0  = (wave & 1) * 32;
    const int mt0 = (wave >> 1) * 4;
    f32x4 acc2[4][2] = {};
    conv2_phase<0, 13>(w2b, sxt, n0, mt0, lane, acc2);
    conv2_phase<13, 12>(w2b, sxt, n0, mt0, lane, acc2);

    {   // horizontal pool in-register -> hb2[oc][50] (overlays hb1)
        #pragma unroll
        for (int mi = 0; mi < 4; ++mi) {
            const int mrow = (mt0 + mi) * 16 + quad * 4;
            if (mrow < 100) {
                #pragma unroll
                for (int np = 0; np < 2; ++np) {
                    const int oc = n0 + np * 16 + col;
                    float2 hm;
                    hm.x = fmaxf(acc2[mi][np][0], acc2[mi][np][1]);
                    hm.y = fmaxf(acc2[mi][np][2], acc2[mi][np][3]);
                    *(float2*)(&hb2[oc * 50 + (mrow >> 1)]) = hm;
                }
            }
        }
    }
    __syncthreads();

    // vertical pool + alpha/bias + tanh -> p2b bf16 [n][1600] (k = oc*25+pix)
    const float a2 = salpha[1];
    for (int idx = t; idx < 1600; idx += 256) {
        const int oc = idx / 25, r = idx - oc * 25;
        const int ph = r / 5, pw = r - ph * 5;
        const float* hb = &hb2[oc * 50 + ph * 10 + pw];
        float m = fmaxf(hb[0], hb[5]);
        p2b[(size_t)n * 1600 + idx] = f2bf(tanh_fast(fmaf(a2, m, b2[oc])));
    }
}

// ---------------------------------------------------------------------------
// conv3 as MFMA GEMM: h3[1024][120] = tanh(a3*(P2 x W3^T) + b3)
template<int STEPS>
__device__ __forceinline__ void conv3_chunk(const ushort* Abase, const ushort* B0,
                                            const ushort* B1, f32x4& acc0, f32x4& acc1) {
    #pragma unroll
    for (int s = 0; s < STEPS; ++s) {
        bf16x8 af = *(const bf16x8*)(Abase + s * 32);
        bf16x8 b0 = *(const bf16x8*)(B0 + s * 32);
        bf16x8 b1 = *(const bf16x8*)(B1 + s * 32);
        acc0 = __builtin_amdgcn_mfma_f32_16x16x32_bf16(af, b0, acc0, 0, 0, 0);
        acc1 = __builtin_amdgcn_mfma_f32_16x16x32_bf16(af, b1, acc1, 0, 0, 0);
    }
}

__global__ __launch_bounds__(256)
void conv3_mfma(const ushort* __restrict__ p2b, const ushort* __restrict__ w3b,
                const float* __restrict__ b3, const float* __restrict__ pb,
                float* __restrict__ h3) {
    __shared__ float red[4][64][8];   // [wave][lane][np*4+reg]
    __shared__ float salpha;
    const int t = threadIdx.x;
    const int wave = t >> 6, lane = t & 63;
    const int mt = blockIdx.x >> 2;       // 0..63
    const int npair = blockIdx.x & 3;     // 0..3
    const int col = lane & 15, quad = lane >> 4;
    const int kstart = (wave < 2) ? wave * 13 : 26 + (wave - 2) * 12;  // 0,13,26,38

    if (t == 0) salpha = alpha_of(pb, 2);

    const ushort* Abase = p2b + (size_t)(mt * 16 + col) * 1600 + kstart * 32 + quad * 8;
    const ushort* B0 = w3b + (size_t)(npair * 32 + col) * 1600 + kstart * 32 + quad * 8;
    const ushort* B1 = B0 + 16 * 1600;

    f32x4 acc0 = {}, acc1 = {};
    if (wave < 2) conv3_chunk<13>(Abase, B0, B1, acc0, acc1);
    else          conv3_chunk<12>(Abase, B0, B1, acc0, acc1);

    #pragma unroll
    for (int r = 0; r < 4; ++r) {
        red[wave][lane][r]     = acc0[r];
        red[wave][lane][4 + r] = acc1[r];
    }
    __syncthreads();

    {   // thread t: lane l = t&63, reg vh = t>>6; handles np = 0 and 1
        const float a3 = salpha;
        const int l = t & 63, vh = t >> 6;
        const int lcol = l & 15, lquad = l >> 4;
        const int img = mt * 16 + lquad * 4 + vh;
        #pragma unroll
        for (int j = 0; j < 2; ++j) {
            const int v = j * 4 + vh;
            float s = red[0][l][v] + red[1][l][v] + red[2][l][v] + red[3][l][v];
            const int oc = npair * 32 + j * 16 + lcol;
            if (oc < 120) h3[(size_t)img * 120 + oc] = tanh_fast(fmaf(a3, s, b3[oc]));
        }
    }
}

// ---------------------------------------------------------------------------
// fc1 + tanh + fc2 + softmax. Block per image; alpha folded.
__global__ __launch_bounds__(128)
void fc_kernel(const float* __restrict__ h3, const float* __restrict__ fw1t,
               const float* __restrict__ fb1, const float* __restrict__ fw2t,
               const float* __restrict__ fb2, const float* __restrict__ pb,
               float* __restrict__ out) {
    const int n = blockIdx.x;
    __shared__ float sh[120];
    __shared__ float sh4[84];
    __shared__ float sl[10];
    __shared__ float salpha[2];
    const int t = threadIdx.x;
    if (t < 120) sh[t] = h3[(size_t)n * 120 + t];
    if (t == 120) salpha[0] = alpha_of(pb, 3);
    if (t == 121) salpha[1] = alpha_of(pb, 4);
    __syncthreads();
    if (t < 84) {
        const float af1 = salpha[0];
        float a = 0.f;
        #pragma unroll 4
        for (int k = 0; k < 120; ++k) a = fmaf(fw1t[k * 84 + t], sh[k], a);
        sh4[t] = tanh_fast(fmaf(af1, a, fb1[t]));
    }
    __syncthreads();
    if (t < 10) {
        const float af2 = salpha[1];
        float a = 0.f;
        #pragma unroll 4
        for (int k = 0; k < 84; ++k) a = fmaf(fw2t[k * 10 + t], sh4[k], a);
        const float lg = fmaf(af2, a, fb2[t]);
        sl[t] = lg;
        out[(size_t)n * 10 + t] = lg;
    }
    __syncthreads();
    if (t < 10) {
        float m = -INFINITY;
        #pragma unroll
        for (int i = 0; i < 10; ++i) m = fmaxf(m, sl[i]);
        float s = 0.f;
        #pragma unroll
        for (int i = 0; i < 10; ++i) s += expf(sl[i] - m);
        out[10240 + (size_t)n * 10 + t] = expf(sl[t] - m) / s;
    }
}

// ---------------------------------------------------------------------------
extern "C" void kernel_launch(void* const* d_in, const int* in_sizes, int n_in,
                              void* d_out, int out_size, void* d_ws, size_t ws_size,
                              hipStream_t stream) {
    const float* x   = (const float*)d_in[0];
    const float* w1  = (const float*)d_in[1];
    const float* b1  = (const float*)d_in[2];
    const float* w2  = (const float*)d_in[3];
    const float* b2  = (const float*)d_in[4];
    const float* w3  = (const float*)d_in[5];
    const float* b3  = (const float*)d_in[6];
    const float* fw1 = (const float*)d_in[7];
    const float* fb1 = (const float*)d_in[8];
    const float* fw2 = (const float*)d_in[9];
    const float* fb2 = (const float*)d_in[10];

    float* ws = (float*)d_ws;
    float*  pb   = ws + OFF_PB;
    ushort* w1b  = (ushort*)(ws + OFF_W1B);
    ushort* w2b  = (ushort*)(ws + OFF_W2B);
    ushort* w3b  = (ushort*)(ws + OFF_W3B);
    float*  fw1t = ws + OFF_FW1T;
    float*  fw2t = ws + OFF_FW2T;
    ushort* p2b  = (ushort*)(ws + OFF_P2B);
    float*  h3   = ws + OFF_H3;
    float*  out  = (float*)d_out;

    tern_pass1<<<5 * BPT, 256, 0, stream>>>(w1, w2, w3, fw1, fw2, pb);
    tern_pass2<<<5 * BPT, 256, 0, stream>>>(w1, w2, w3, fw1, fw2,
                                            w1b, w2b, w3b, fw1t, fw2t, pb);
    conv12_kernel<<<1024, 256, 0, stream>>>(x, w1b, b1, w2b, b2, pb, p2b);
    conv3_mfma<<<256, 256, 0, stream>>>(p2b, w3b, b3, pb, h3);
    fc_kernel<<<1024, 128, 0, stream>>>(h3, fw1t, fb1, fw2t, fb2, pb, out);
}